// Round 11
// baseline (310.703 us; speedup 1.0000x reference)
//
#include <hip/hip_runtime.h>
#include <hip/hip_bf16.h>
#include <math.h>

#define NB 37
#define BB 4
#define CC 2
#define FF 1025
#define TT 2048
#define EE 128
#define DD 260
#define EPSF 1e-5f
#define CHS 9           // max K chunks of 32 (Kpad<=288)

typedef short s16x8 __attribute__((ext_vector_type(8)));
typedef float f32x4 __attribute__((ext_vector_type(4)));
typedef const unsigned int __attribute__((address_space(1))) gu32;
typedef unsigned int __attribute__((address_space(3))) lu32;

__device__ __forceinline__ unsigned short f2bf(float f) {
    unsigned u = __builtin_bit_cast(unsigned, f);
    unsigned r = (u + 0x7FFFu + ((u >> 16) & 1u)) >> 16;
    return (unsigned short)r;
}

// ---------------------------------------------------------------------------
// Kernel 1: per-band prep (unchanged).
// A[e,k] = gamma[d(k)] * g[e]*v[e,d(k)]/||v[e]||, ATg layout [n][ch][e][32k],
// zero-padded within partial chunks. s1[e]=sum A, s2p[e]=sum beta*W + bias.
// ---------------------------------------------------------------------------
__global__ __launch_bounds__(256) void prep_kernel(
    const float* __restrict__ gamma, const float* __restrict__ beta,
    const float* __restrict__ v, const float* __restrict__ g,
    const float* __restrict__ bias, const int* __restrict__ bwidth,
    unsigned short* __restrict__ ATg, float* __restrict__ s1o, float* __restrict__ s2o)
{
    int bid = blockIdx.x;
    int n   = bid >> 4;
    int eg  = bid & 15;
    int tid = threadIdx.x;
    int el  = tid >> 5;          // 0..7
    int kk  = tid & 31;
    int e   = eg * 8 + el;

    int bw    = bwidth[n];
    int Deff  = 4 * bw;
    int twobw = 2 * bw;
    int nCh   = (Deff + 31) >> 5;

    const float* vp = v + (size_t)(n * EE + e) * DD;

    float sq = 0.f;
    for (int d = kk; d < DD; d += 32) { float val = vp[d]; sq = fmaf(val, val, sq); }
    #pragma unroll
    for (int m = 16; m >= 1; m >>= 1) sq += __shfl_xor(sq, m);

    float rv = g[n * EE + e] * rsqrtf(sq);

    float s1 = 0.f, s2 = 0.f;
    unsigned short* Abase = ATg + (size_t)n * CHS * (EE * 32) + e * 32 + kk;
    for (int ch = 0; ch < nCh; ++ch) {
        int k = ch * 32 + kk;
        float a = 0.f;
        if (k < Deff) {
            int d = (k >= twobw) ? (130 + k - twobw) : k;
            float W = rv * vp[d];
            a = gamma[n * DD + d] * W;
            s1 += a;
            s2 = fmaf(beta[n * DD + d], W, s2);
        }
        Abase[(size_t)ch * (EE * 32)] = f2bf(a);
    }
    #pragma unroll
    for (int m = 16; m >= 1; m >>= 1) { s1 += __shfl_xor(s1, m); s2 += __shfl_xor(s2, m); }
    if (kk == 0) {
        s1o[n * EE + e] = s1;
        s2o[n * EE + e] = s2 + bias[n * EE + e];
    }
}

// ---------------------------------------------------------------------------
// Kernel 2: fused stats + MFMA GEMM. Block = (b, n, 256-t slab), 4 waves
// (64t x 64e each per 128-t subtile). 2 x 16KB LDS buffers -> 5 blocks/CU;
// grid 1184 = fully co-resident (no dispatch churn). Per chunk-step:
//   s_waitcnt vmcnt(0); s_barrier; sched_barrier(0)   // buf ready, all rows
//   A-frag loads (pinned older than STAGE -> pre-MFMA wait = vmcnt(4))
//   STAGE(next chunk / next subtile) into other buf
//   compute (ds_read + stats + 16 MFMA)
// Subtile flush (stats finalize + stores) covers the cross-subtile DMA.
// ---------------------------------------------------------------------------
__global__ __launch_bounds__(256, 5) void fused_kernel(
    const float* __restrict__ x, const int* __restrict__ bstart,
    const int* __restrict__ bwidth,
    const unsigned short* __restrict__ ATg, const float* __restrict__ s1a,
    const float* __restrict__ s2a, float* __restrict__ out)
{
    int bid  = blockIdx.x;
    int n    = bid % NB;                // fastest -> uniform band mix over CUs
    int rest = bid / NB;
    int sl   = rest & 7;                // T/256 = 8 slabs
    int b    = rest >> 3;
    int t0   = sl * 256;
    int f0   = bstart[n];
    int bw   = bwidth[n];
    int nPairs = 2 * bw;
    int Deff   = 4 * bw;
    int nChF   = Deff >> 5;             // 2,4,8,8
    int remP   = nPairs - nChF * 16;    // 2 for band 36, else 0
    int nChT   = nChF + (remP ? 1 : 0);

    int tid   = threadIdx.x;
    int lane  = tid & 63;
    int l15   = lane & 15;
    int ksub  = lane >> 4;
    int wv    = tid >> 6;
    int tband = (wv >> 1) * 64;         // t base within 128-t subtile
    int ewave = (wv & 1) * 64;

    __shared__ __align__(16) float Xs[2 * 4096];   // 2 x 16KB chunk buffers

    const char* xbase = (const char*)x;

    auto STAGE = [&](int ts, int ch, int bufOff) {
        #pragma unroll
        for (int j = 0; j < 4; ++j) {
            int pl = wv * 4 + j;
            int p  = ch * 16 + pl;
            p = (p < nPairs) ? p : (nPairs - 1);      // clamp (tail); masked later
            int c   = (p >= bw) ? 1 : 0;
            int row = (b * CC + c) * FF + f0 + (p - c * bw);
            const char* gsrc = xbase + (size_t)row * 16384
                             + (size_t)(t0 + ts * 128) * 8 + (size_t)lane * 16;
            __builtin_amdgcn_global_load_lds(
                (gu32*)gsrc, (lu32*)(Xs + bufOff + pl * 256), 16, 0, 0);
        }
    };

    const s16x8* Ab = reinterpret_cast<const s16x8*>(
        ATg + (size_t)n * CHS * (EE * 32)) + ((ewave + l15) * 4 + ksub);

    f32x4 acc[4][4];
    #pragma unroll
    for (int mi = 0; mi < 4; ++mi)
        #pragma unroll
        for (int ni = 0; ni < 4; ++ni)
            acc[mi][ni] = (f32x4){0.f, 0.f, 0.f, 0.f};
    float sA[4] = {0.f, 0.f, 0.f, 0.f};
    float qA[4] = {0.f, 0.f, 0.f, 0.f};

    STAGE(0, 0, 0);
    int bufOff = 0;

    for (int ts = 0; ts < 2; ++ts) {
        for (int ch = 0; ch < nChT; ++ch) {
            asm volatile("s_waitcnt vmcnt(0)" ::: "memory");
            __builtin_amdgcn_s_barrier();
            __builtin_amdgcn_sched_barrier(0);

            // A fragments for this chunk (L1/L2-hot; older than STAGE below)
            s16x8 a0 = Ab[ch * 512];
            s16x8 a1 = Ab[ch * 512 + 64];
            s16x8 a2 = Ab[ch * 512 + 128];
            s16x8 a3 = Ab[ch * 512 + 192];
            __builtin_amdgcn_sched_barrier(0);

            if (ch + 1 < nChT)  STAGE(ts, ch + 1, bufOff ^ 4096);
            else if (ts == 0)   STAGE(1, 0, bufOff ^ 4096);

            const float2* Xp = reinterpret_cast<const float2*>(Xs + bufOff);
            bool tail = (ch == nChF);   // only reachable when remP > 0

            #pragma unroll
            for (int mi = 0; mi < 4; ++mi) {
                float2 vv[4];
                #pragma unroll
                for (int j = 0; j < 4; ++j)
                    vv[j] = Xp[(4 * ksub + j) * 128 + tband + mi * 16 + l15];
                if (tail) {
                    #pragma unroll
                    for (int j = 0; j < 4; ++j)
                        if (4 * ksub + j >= remP) vv[j] = make_float2(0.f, 0.f);
                }
                float s = 0.f, q = 0.f;
                union { s16x8 v; __hip_bfloat162 h[4]; } afu;
                #pragma unroll
                for (int j = 0; j < 4; ++j) {
                    s += vv[j].x + vv[j].y;
                    q = fmaf(vv[j].x, vv[j].x, q);
                    q = fmaf(vv[j].y, vv[j].y, q);
                    afu.h[j] = __float22bfloat162_rn(make_float2(vv[j].x, vv[j].y));
                }
                sA[mi] += s;
                qA[mi] += q;
                s16x8 af = afu.v;
                acc[mi][0] = __builtin_amdgcn_mfma_f32_16x16x32_bf16(af, a0, acc[mi][0], 0, 0, 0);
                acc[mi][1] = __builtin_amdgcn_mfma_f32_16x16x32_bf16(af, a1, acc[mi][1], 0, 0, 0);
                acc[mi][2] = __builtin_amdgcn_mfma_f32_16x16x32_bf16(af, a2, acc[mi][2], 0, 0, 0);
                acc[mi][3] = __builtin_amdgcn_mfma_f32_16x16x32_bf16(af, a3, acc[mi][3], 0, 0, 0);
            }
            bufOff ^= 4096;
        }

        // ---- subtile flush: stats finalize + epilogue (covers next-slab DMA)
        float inv = 1.f / (float)Deff;
        float mrow[4][4], rrow[4][4];
        #pragma unroll
        for (int mi = 0; mi < 4; ++mi) {
            float s = sA[mi], q = qA[mi];
            s += __shfl_xor(s, 16); s += __shfl_xor(s, 32);
            q += __shfl_xor(q, 16); q += __shfl_xor(q, 32);
            float mean = s * inv;
            float var  = fmaf(q, inv, -mean * mean);
            float rs   = rsqrtf(var + EPSF);
            #pragma unroll
            for (int j = 0; j < 4; ++j) {
                int src = (ksub << 2) + j;
                mrow[mi][j] = __shfl(mean, src);
                rrow[mi][j] = __shfl(rs, src);
            }
        }

        float s1r[4], s2r[4];
        #pragma unroll
        for (int ni = 0; ni < 4; ++ni) {
            int e = ewave + ni * 16 + l15;
            s1r[ni] = s1a[n * EE + e];
            s2r[ni] = s2a[n * EE + e];
        }
        size_t outRow = ((size_t)(b * NB + n)) * TT;
        #pragma unroll
        for (int mi = 0; mi < 4; ++mi) {
            #pragma unroll
            for (int j = 0; j < 4; ++j) {
                int t = t0 + ts * 128 + tband + mi * 16 + (ksub << 2) + j;
                float m = mrow[mi][j], r = rrow[mi][j];
                float* op = out + (outRow + t) * EE + ewave + l15;
                #pragma unroll
                for (int ni = 0; ni < 4; ++ni)
                    op[ni * 16] = fmaf(r, acc[mi][ni][j] - m * s1r[ni], s2r[ni]);
            }
            #pragma unroll
            for (int ni = 0; ni < 4; ++ni)
                acc[mi][ni] = (f32x4){0.f, 0.f, 0.f, 0.f};
            sA[mi] = 0.f; qA[mi] = 0.f;
        }
    }
}

// ---------------------------------------------------------------------------
extern "C" void kernel_launch(void* const* d_in, const int* in_sizes, int n_in,
                              void* d_out, int out_size, void* d_ws, size_t ws_size,
                              hipStream_t stream)
{
    const float* x      = (const float*)d_in[0];
    const float* gamma  = (const float*)d_in[1];
    const float* beta   = (const float*)d_in[2];
    const float* v      = (const float*)d_in[3];
    const float* g      = (const float*)d_in[4];
    const float* bias   = (const float*)d_in[5];
    const int*   bstart = (const int*)d_in[6];
    const int*   bwidth = (const int*)d_in[7];
    float* out = (float*)d_out;

    unsigned short* ATg = (unsigned short*)d_ws;                 // 37*9*128*32 bf16
    float* s1  = (float*)(ATg + (size_t)NB * CHS * EE * 32);     // 37*128 f32
    float* s2p = s1 + NB * EE;                                   // 37*128 f32

    prep_kernel<<<NB * 16, 256, 0, stream>>>(gamma, beta, v, g, bias, bwidth, ATg, s1, s2p);
    fused_kernel<<<BB * NB * 8, 256, 0, stream>>>(x, bstart, bwidth, ATg, s1, s2p, out);
}

// Round 12
// 230.087 us; speedup vs baseline: 1.3504x; 1.3504x over previous
//
#include <hip/hip_runtime.h>
#include <hip/hip_bf16.h>
#include <math.h>

#define NB 37
#define BB 4
#define CC 2
#define FF 1025
#define TT 2048
#define EE 128
#define DD 260
#define EPSF 1e-5f
#define CHS 9           // max K chunks of 32 (Kpad<=288)

typedef short s16x8 __attribute__((ext_vector_type(8)));
typedef float f32x4 __attribute__((ext_vector_type(4)));
typedef const unsigned int __attribute__((address_space(1))) gu32;
typedef unsigned int __attribute__((address_space(3))) lu32;

__device__ __forceinline__ unsigned short f2bf(float f) {
    unsigned u = __builtin_bit_cast(unsigned, f);
    unsigned r = (u + 0x7FFFu + ((u >> 16) & 1u)) >> 16;
    return (unsigned short)r;
}

// ---------------------------------------------------------------------------
// Kernel 1: per-band prep (unchanged).
// A[e,k] = gamma[d(k)] * g[e]*v[e,d(k)]/||v[e]||, ATg layout [n][ch][e][32k],
// zero-padded within partial chunks. s1[e]=sum A, s2p[e]=sum beta*W + bias.
// ---------------------------------------------------------------------------
__global__ __launch_bounds__(256) void prep_kernel(
    const float* __restrict__ gamma, const float* __restrict__ beta,
    const float* __restrict__ v, const float* __restrict__ g,
    const float* __restrict__ bias, const int* __restrict__ bwidth,
    unsigned short* __restrict__ ATg, float* __restrict__ s1o, float* __restrict__ s2o)
{
    int bid = blockIdx.x;
    int n   = bid >> 4;
    int eg  = bid & 15;
    int tid = threadIdx.x;
    int el  = tid >> 5;          // 0..7
    int kk  = tid & 31;
    int e   = eg * 8 + el;

    int bw    = bwidth[n];
    int Deff  = 4 * bw;
    int twobw = 2 * bw;
    int nCh   = (Deff + 31) >> 5;

    const float* vp = v + (size_t)(n * EE + e) * DD;

    float sq = 0.f;
    for (int d = kk; d < DD; d += 32) { float val = vp[d]; sq = fmaf(val, val, sq); }
    #pragma unroll
    for (int m = 16; m >= 1; m >>= 1) sq += __shfl_xor(sq, m);

    float rv = g[n * EE + e] * rsqrtf(sq);

    float s1 = 0.f, s2 = 0.f;
    unsigned short* Abase = ATg + (size_t)n * CHS * (EE * 32) + e * 32 + kk;
    for (int ch = 0; ch < nCh; ++ch) {
        int k = ch * 32 + kk;
        float a = 0.f;
        if (k < Deff) {
            int d = (k >= twobw) ? (130 + k - twobw) : k;
            float W = rv * vp[d];
            a = gamma[n * DD + d] * W;
            s1 += a;
            s2 = fmaf(beta[n * DD + d], W, s2);
        }
        Abase[(size_t)ch * (EE * 32)] = f2bf(a);
    }
    #pragma unroll
    for (int m = 16; m >= 1; m >>= 1) { s1 += __shfl_xor(s1, m); s2 += __shfl_xor(s2, m); }
    if (kk == 0) {
        s1o[n * EE + e] = s1;
        s2o[n * EE + e] = s2 + bias[n * EE + e];
    }
}

// ---------------------------------------------------------------------------
// Kernel 2: fused stats + MFMA GEMM. Block = (b, n, 256-t slab), 4 waves
// (64t x 64e each per 128-t subtile). 2 x 16KB LDS buffers; grid 1184.
// launch_bounds min-waves=4: R11's =5 forced the allocator to 48 VGPR and
// spilled the accumulator (FETCH+WRITE tripled). 4 leaves ~88 VGPR live,
// which still hardware-allows 5 waves/SIMD (5*88 <= 512).
// Per chunk-step:
//   s_waitcnt vmcnt(0); s_barrier; sched_barrier(0)   // buf ready, all rows
//   A-frag loads (pinned older than STAGE -> pre-MFMA wait = vmcnt(4))
//   STAGE(next chunk / next subtile) into other buf
//   compute (ds_read + stats + 16 MFMA)
// Subtile flush (stats finalize + stores) covers the cross-subtile DMA.
// ---------------------------------------------------------------------------
__global__ __launch_bounds__(256, 4) void fused_kernel(
    const float* __restrict__ x, const int* __restrict__ bstart,
    const int* __restrict__ bwidth,
    const unsigned short* __restrict__ ATg, const float* __restrict__ s1a,
    const float* __restrict__ s2a, float* __restrict__ out)
{
    int bid  = blockIdx.x;
    int n    = bid % NB;                // fastest -> uniform band mix over CUs
    int rest = bid / NB;
    int sl   = rest & 7;                // T/256 = 8 slabs
    int b    = rest >> 3;
    int t0   = sl * 256;
    int f0   = bstart[n];
    int bw   = bwidth[n];
    int nPairs = 2 * bw;
    int Deff   = 4 * bw;
    int nChF   = Deff >> 5;             // 2,4,8,8
    int remP   = nPairs - nChF * 16;    // 2 for band 36, else 0
    int nChT   = nChF + (remP ? 1 : 0);

    int tid   = threadIdx.x;
    int lane  = tid & 63;
    int l15   = lane & 15;
    int ksub  = lane >> 4;
    int wv    = tid >> 6;
    int tband = (wv >> 1) * 64;         // t base within 128-t subtile
    int ewave = (wv & 1) * 64;

    __shared__ __align__(16) float Xs[2 * 4096];   // 2 x 16KB chunk buffers

    const char* xbase = (const char*)x;

    auto STAGE = [&](int ts, int ch, int bufOff) {
        #pragma unroll
        for (int j = 0; j < 4; ++j) {
            int pl = wv * 4 + j;
            int p  = ch * 16 + pl;
            p = (p < nPairs) ? p : (nPairs - 1);      // clamp (tail); masked later
            int c   = (p >= bw) ? 1 : 0;
            int row = (b * CC + c) * FF + f0 + (p - c * bw);
            const char* gsrc = xbase + (size_t)row * 16384
                             + (size_t)(t0 + ts * 128) * 8 + (size_t)lane * 16;
            __builtin_amdgcn_global_load_lds(
                (gu32*)gsrc, (lu32*)(Xs + bufOff + pl * 256), 16, 0, 0);
        }
    };

    const s16x8* Ab = reinterpret_cast<const s16x8*>(
        ATg + (size_t)n * CHS * (EE * 32)) + ((ewave + l15) * 4 + ksub);

    f32x4 acc[4][4];
    #pragma unroll
    for (int mi = 0; mi < 4; ++mi)
        #pragma unroll
        for (int ni = 0; ni < 4; ++ni)
            acc[mi][ni] = (f32x4){0.f, 0.f, 0.f, 0.f};
    float sA[4] = {0.f, 0.f, 0.f, 0.f};
    float qA[4] = {0.f, 0.f, 0.f, 0.f};

    STAGE(0, 0, 0);
    int bufOff = 0;

    for (int ts = 0; ts < 2; ++ts) {
        for (int ch = 0; ch < nChT; ++ch) {
            asm volatile("s_waitcnt vmcnt(0)" ::: "memory");
            __builtin_amdgcn_s_barrier();
            __builtin_amdgcn_sched_barrier(0);

            // A fragments for this chunk (L1/L2-hot; older than STAGE below)
            s16x8 a0 = Ab[ch * 512];
            s16x8 a1 = Ab[ch * 512 + 64];
            s16x8 a2 = Ab[ch * 512 + 128];
            s16x8 a3 = Ab[ch * 512 + 192];
            __builtin_amdgcn_sched_barrier(0);

            if (ch + 1 < nChT)  STAGE(ts, ch + 1, bufOff ^ 4096);
            else if (ts == 0)   STAGE(1, 0, bufOff ^ 4096);

            const float2* Xp = reinterpret_cast<const float2*>(Xs + bufOff);
            bool tail = (ch == nChF);   // only reachable when remP > 0

            #pragma unroll
            for (int mi = 0; mi < 4; ++mi) {
                float2 vv[4];
                #pragma unroll
                for (int j = 0; j < 4; ++j)
                    vv[j] = Xp[(4 * ksub + j) * 128 + tband + mi * 16 + l15];
                if (tail) {
                    #pragma unroll
                    for (int j = 0; j < 4; ++j)
                        if (4 * ksub + j >= remP) vv[j] = make_float2(0.f, 0.f);
                }
                float s = 0.f, q = 0.f;
                union { s16x8 v; __hip_bfloat162 h[4]; } afu;
                #pragma unroll
                for (int j = 0; j < 4; ++j) {
                    s += vv[j].x + vv[j].y;
                    q = fmaf(vv[j].x, vv[j].x, q);
                    q = fmaf(vv[j].y, vv[j].y, q);
                    afu.h[j] = __float22bfloat162_rn(make_float2(vv[j].x, vv[j].y));
                }
                sA[mi] += s;
                qA[mi] += q;
                s16x8 af = afu.v;
                acc[mi][0] = __builtin_amdgcn_mfma_f32_16x16x32_bf16(af, a0, acc[mi][0], 0, 0, 0);
                acc[mi][1] = __builtin_amdgcn_mfma_f32_16x16x32_bf16(af, a1, acc[mi][1], 0, 0, 0);
                acc[mi][2] = __builtin_amdgcn_mfma_f32_16x16x32_bf16(af, a2, acc[mi][2], 0, 0, 0);
                acc[mi][3] = __builtin_amdgcn_mfma_f32_16x16x32_bf16(af, a3, acc[mi][3], 0, 0, 0);
            }
            bufOff ^= 4096;
        }

        // ---- subtile flush: stats finalize + epilogue (covers next-slab DMA)
        float inv = 1.f / (float)Deff;
        float mrow[4][4], rrow[4][4];
        #pragma unroll
        for (int mi = 0; mi < 4; ++mi) {
            float s = sA[mi], q = qA[mi];
            s += __shfl_xor(s, 16); s += __shfl_xor(s, 32);
            q += __shfl_xor(q, 16); q += __shfl_xor(q, 32);
            float mean = s * inv;
            float var  = fmaf(q, inv, -mean * mean);
            float rs   = rsqrtf(var + EPSF);
            #pragma unroll
            for (int j = 0; j < 4; ++j) {
                int src = (ksub << 2) + j;
                mrow[mi][j] = __shfl(mean, src);
                rrow[mi][j] = __shfl(rs, src);
            }
        }

        float s1r[4], s2r[4];
        #pragma unroll
        for (int ni = 0; ni < 4; ++ni) {
            int e = ewave + ni * 16 + l15;
            s1r[ni] = s1a[n * EE + e];
            s2r[ni] = s2a[n * EE + e];
        }
        size_t outRow = ((size_t)(b * NB + n)) * TT;
        #pragma unroll
        for (int mi = 0; mi < 4; ++mi) {
            #pragma unroll
            for (int j = 0; j < 4; ++j) {
                int t = t0 + ts * 128 + tband + mi * 16 + (ksub << 2) + j;
                float m = mrow[mi][j], r = rrow[mi][j];
                float* op = out + (outRow + t) * EE + ewave + l15;
                #pragma unroll
                for (int ni = 0; ni < 4; ++ni)
                    op[ni * 16] = fmaf(r, acc[mi][ni][j] - m * s1r[ni], s2r[ni]);
            }
            #pragma unroll
            for (int ni = 0; ni < 4; ++ni)
                acc[mi][ni] = (f32x4){0.f, 0.f, 0.f, 0.f};
            sA[mi] = 0.f; qA[mi] = 0.f;
        }
    }
}

// ---------------------------------------------------------------------------
extern "C" void kernel_launch(void* const* d_in, const int* in_sizes, int n_in,
                              void* d_out, int out_size, void* d_ws, size_t ws_size,
                              hipStream_t stream)
{
    const float* x      = (const float*)d_in[0];
    const float* gamma  = (const float*)d_in[1];
    const float* beta   = (const float*)d_in[2];
    const float* v      = (const float*)d_in[3];
    const float* g      = (const float*)d_in[4];
    const float* bias   = (const float*)d_in[5];
    const int*   bstart = (const int*)d_in[6];
    const int*   bwidth = (const int*)d_in[7];
    float* out = (float*)d_out;

    unsigned short* ATg = (unsigned short*)d_ws;                 // 37*9*128*32 bf16
    float* s1  = (float*)(ATg + (size_t)NB * CHS * EE * 32);     // 37*128 f32
    float* s2p = s1 + NB * EE;                                   // 37*128 f32

    prep_kernel<<<NB * 16, 256, 0, stream>>>(gamma, beta, v, g, bias, bwidth, ATg, s1, s2p);
    fused_kernel<<<BB * NB * 8, 256, 0, stream>>>(x, bstart, bwidth, ATg, s1, s2p, out);
}

// Round 13
// 78.495 us; speedup vs baseline: 3.9582x; 2.9312x over previous
//
#include <hip/hip_runtime.h>
#include <hip/hip_bf16.h>
#include <math.h>

#define NB 37
#define BB 4
#define CC 2
#define FF 1025
#define TT 2048
#define EE 128
#define DD 260
#define EPSF 1e-5f
#define CHS 9           // max K chunks of 32 (Kpad<=288)

typedef short s16x8 __attribute__((ext_vector_type(8)));
typedef float f32x4 __attribute__((ext_vector_type(4)));
typedef const unsigned int __attribute__((address_space(1))) gu32;
typedef unsigned int __attribute__((address_space(3))) lu32;

__device__ __forceinline__ unsigned short f2bf(float f) {
    unsigned u = __builtin_bit_cast(unsigned, f);
    unsigned r = (u + 0x7FFFu + ((u >> 16) & 1u)) >> 16;
    return (unsigned short)r;
}

// ---------------------------------------------------------------------------
// Kernel 1: per-band prep (unchanged).
// A[e,k] = gamma[d(k)] * g[e]*v[e,d(k)]/||v[e]||, ATg layout [n][ch][e][32k],
// zero-padded within partial chunks. s1[e]=sum A, s2p[e]=sum beta*W + bias.
// ---------------------------------------------------------------------------
__global__ __launch_bounds__(256) void prep_kernel(
    const float* __restrict__ gamma, const float* __restrict__ beta,
    const float* __restrict__ v, const float* __restrict__ g,
    const float* __restrict__ bias, const int* __restrict__ bwidth,
    unsigned short* __restrict__ ATg, float* __restrict__ s1o, float* __restrict__ s2o)
{
    int bid = blockIdx.x;
    int n   = bid >> 4;
    int eg  = bid & 15;
    int tid = threadIdx.x;
    int el  = tid >> 5;          // 0..7
    int kk  = tid & 31;
    int e   = eg * 8 + el;

    int bw    = bwidth[n];
    int Deff  = 4 * bw;
    int twobw = 2 * bw;
    int nCh   = (Deff + 31) >> 5;

    const float* vp = v + (size_t)(n * EE + e) * DD;

    float sq = 0.f;
    for (int d = kk; d < DD; d += 32) { float val = vp[d]; sq = fmaf(val, val, sq); }
    #pragma unroll
    for (int m = 16; m >= 1; m >>= 1) sq += __shfl_xor(sq, m);

    float rv = g[n * EE + e] * rsqrtf(sq);

    float s1 = 0.f, s2 = 0.f;
    unsigned short* Abase = ATg + (size_t)n * CHS * (EE * 32) + e * 32 + kk;
    for (int ch = 0; ch < nCh; ++ch) {
        int k = ch * 32 + kk;
        float a = 0.f;
        if (k < Deff) {
            int d = (k >= twobw) ? (130 + k - twobw) : k;
            float W = rv * vp[d];
            a = gamma[n * DD + d] * W;
            s1 += a;
            s2 = fmaf(beta[n * DD + d], W, s2);
        }
        Abase[(size_t)ch * (EE * 32)] = f2bf(a);
    }
    #pragma unroll
    for (int m = 16; m >= 1; m >>= 1) { s1 += __shfl_xor(s1, m); s2 += __shfl_xor(s2, m); }
    if (kk == 0) {
        s1o[n * EE + e] = s1;
        s2o[n * EE + e] = s2 + bias[n * EE + e];
    }
}

// ---------------------------------------------------------------------------
// Kernel 2: fused stats + MFMA GEMM, chunk-PAIR bursts. Block = 128t x 128e,
// 4 waves. 2 x 32KB LDS buffers. Per pipeline step:
//   s_waitcnt vmcnt(0); s_barrier; sched_barrier(0)   // pair buf ready
//   A-frag loads for BOTH chunks (8 loads)
//   STAGE_PAIR(cp+1) -> other buf (8 DMAs/wave, 8KB in flight during compute)
//   compute chunk 2cp, chunk 2cp+1 (32 MFMA)
// bw65 tail (2 rows) handled as a separate final step.
// ---------------------------------------------------------------------------
__global__ __launch_bounds__(256) void fused_kernel(
    const float* __restrict__ x, const int* __restrict__ bstart,
    const int* __restrict__ bwidth,
    const unsigned short* __restrict__ ATg, const float* __restrict__ s1a,
    const float* __restrict__ s2a, float* __restrict__ out)
{
    int bid  = blockIdx.x;
    int n    = bid % NB;                // fastest -> uniform band mix over CUs
    int rest = bid / NB;
    int tt   = rest & 15;               // T/128 = 16
    int b    = rest >> 4;
    int t0   = tt * 128;
    int f0   = bstart[n];
    int bw   = bwidth[n];
    int nPairs = 2 * bw;                // x pair-rows in band
    int nChF   = (4 * bw) >> 5;         // full chunks: 2,4,8,8
    int nPairF = nChF >> 1;             // full chunk-pairs: 1,2,4,4
    int remP   = nPairs - nChF * 16;    // 2 for band 36, else 0

    int tid   = threadIdx.x;
    int lane  = tid & 63;
    int l15   = lane & 15;
    int ksub  = lane >> 4;
    int wv    = tid >> 6;
    int tband = (wv >> 1) * 64;
    int ewave = (wv & 1) * 64;

    __shared__ __align__(16) float Xs[2 * 8192];   // 2 x 32KB pair buffers

    const char* xbase = (const char*)x;

    // stage chunk-pair cp: 32 pair-rows, 8 per wave
    auto STAGE = [&](int cp, int bufOff) {
        #pragma unroll
        for (int j = 0; j < 8; ++j) {
            int pl = wv * 8 + j;
            int p  = cp * 32 + pl;               // < nPairs for all full pairs
            int c   = (p >= bw) ? 1 : 0;
            int row = (b * CC + c) * FF + f0 + (p - c * bw);
            const char* gsrc = xbase + (size_t)row * 16384 + (size_t)t0 * 8
                             + (size_t)lane * 16;
            __builtin_amdgcn_global_load_lds(
                (gu32*)gsrc, (lu32*)(Xs + bufOff + pl * 256), 16, 0, 0);
        }
    };
    // stage the 2-row tail (bw=65 only): rows 128,129 -> wave 0
    auto STAGE_TAIL = [&](int bufOff) {
        if (wv == 0) {
            #pragma unroll
            for (int j = 0; j < 2; ++j) {
                int p   = nChF * 16 + j;         // 128,129
                int c   = (p >= bw) ? 1 : 0;
                int row = (b * CC + c) * FF + f0 + (p - c * bw);
                const char* gsrc = xbase + (size_t)row * 16384 + (size_t)t0 * 8
                                 + (size_t)lane * 16;
                __builtin_amdgcn_global_load_lds(
                    (gu32*)gsrc, (lu32*)(Xs + bufOff + j * 256), 16, 0, 0);
            }
        }
    };

    const s16x8* Ab = reinterpret_cast<const s16x8*>(
        ATg + (size_t)n * CHS * (EE * 32)) + ((ewave + l15) * 4 + ksub);

    f32x4 acc[4][4];
    #pragma unroll
    for (int mi = 0; mi < 4; ++mi)
        #pragma unroll
        for (int ni = 0; ni < 4; ++ni)
            acc[mi][ni] = (f32x4){0.f, 0.f, 0.f, 0.f};
    float sA[4] = {0.f, 0.f, 0.f, 0.f};
    float qA[4] = {0.f, 0.f, 0.f, 0.f};

    STAGE(0, 0);
    int bufOff = 0;

    for (int cp = 0; cp < nPairF; ++cp) {
        asm volatile("s_waitcnt vmcnt(0)" ::: "memory");
        __builtin_amdgcn_s_barrier();
        __builtin_amdgcn_sched_barrier(0);

        // A fragments for both chunks of this pair (older than new STAGE)
        int ch0 = 2 * cp;
        s16x8 a00 = Ab[ch0 * 512];       s16x8 a01 = Ab[ch0 * 512 + 64];
        s16x8 a02 = Ab[ch0 * 512 + 128]; s16x8 a03 = Ab[ch0 * 512 + 192];
        s16x8 a10 = Ab[ch0 * 512 + 512]; s16x8 a11 = Ab[ch0 * 512 + 576];
        s16x8 a12 = Ab[ch0 * 512 + 640]; s16x8 a13 = Ab[ch0 * 512 + 704];
        __builtin_amdgcn_sched_barrier(0);

        if (cp + 1 < nPairF)       STAGE(cp + 1, bufOff ^ 8192);
        else if (remP)             STAGE_TAIL(bufOff ^ 8192);

        #pragma unroll
        for (int cc = 0; cc < 2; ++cc) {
            const float2* Xp = reinterpret_cast<const float2*>(Xs + bufOff + cc * 4096);
            s16x8 aw0 = cc ? a10 : a00, aw1 = cc ? a11 : a01;
            s16x8 aw2 = cc ? a12 : a02, aw3 = cc ? a13 : a03;
            #pragma unroll
            for (int mi = 0; mi < 4; ++mi) {
                float2 vv[4];
                #pragma unroll
                for (int j = 0; j < 4; ++j)
                    vv[j] = Xp[(4 * ksub + j) * 128 + tband + mi * 16 + l15];
                float s = 0.f, q = 0.f;
                union { s16x8 v; __hip_bfloat162 h[4]; } afu;
                #pragma unroll
                for (int j = 0; j < 4; ++j) {
                    s += vv[j].x + vv[j].y;
                    q = fmaf(vv[j].x, vv[j].x, q);
                    q = fmaf(vv[j].y, vv[j].y, q);
                    afu.h[j] = __float22bfloat162_rn(make_float2(vv[j].x, vv[j].y));
                }
                sA[mi] += s;
                qA[mi] += q;
                s16x8 af = afu.v;
                acc[mi][0] = __builtin_amdgcn_mfma_f32_16x16x32_bf16(af, aw0, acc[mi][0], 0, 0, 0);
                acc[mi][1] = __builtin_amdgcn_mfma_f32_16x16x32_bf16(af, aw1, acc[mi][1], 0, 0, 0);
                acc[mi][2] = __builtin_amdgcn_mfma_f32_16x16x32_bf16(af, aw2, acc[mi][2], 0, 0, 0);
                acc[mi][3] = __builtin_amdgcn_mfma_f32_16x16x32_bf16(af, aw3, acc[mi][3], 0, 0, 0);
            }
        }
        bufOff ^= 8192;
    }

    // ---- tail step (bw=65 only): chunk nChF, 2 valid pair-rows
    if (remP) {
        asm volatile("s_waitcnt vmcnt(0)" ::: "memory");
        __builtin_amdgcn_s_barrier();
        __builtin_amdgcn_sched_barrier(0);
        int ch = nChF;
        s16x8 a0 = Ab[ch * 512];       s16x8 a1 = Ab[ch * 512 + 64];
        s16x8 a2 = Ab[ch * 512 + 128]; s16x8 a3 = Ab[ch * 512 + 192];
        const float2* Xp = reinterpret_cast<const float2*>(Xs + bufOff);
        #pragma unroll
        for (int mi = 0; mi < 4; ++mi) {
            float2 vv[4];
            #pragma unroll
            for (int j = 0; j < 4; ++j) {
                int pl = 4 * ksub + j;
                vv[j] = make_float2(0.f, 0.f);
                if (pl < 2)   // remP == 2
                    vv[j] = Xp[pl * 128 + tband + mi * 16 + l15];
            }
            float s = 0.f, q = 0.f;
            union { s16x8 v; __hip_bfloat162 h[4]; } afu;
            #pragma unroll
            for (int j = 0; j < 4; ++j) {
                s += vv[j].x + vv[j].y;
                q = fmaf(vv[j].x, vv[j].x, q);
                q = fmaf(vv[j].y, vv[j].y, q);
                afu.h[j] = __float22bfloat162_rn(make_float2(vv[j].x, vv[j].y));
            }
            sA[mi] += s;
            qA[mi] += q;
            s16x8 af = afu.v;
            acc[mi][0] = __builtin_amdgcn_mfma_f32_16x16x32_bf16(af, a0, acc[mi][0], 0, 0, 0);
            acc[mi][1] = __builtin_amdgcn_mfma_f32_16x16x32_bf16(af, a1, acc[mi][1], 0, 0, 0);
            acc[mi][2] = __builtin_amdgcn_mfma_f32_16x16x32_bf16(af, a2, acc[mi][2], 0, 0, 0);
            acc[mi][3] = __builtin_amdgcn_mfma_f32_16x16x32_bf16(af, a3, acc[mi][3], 0, 0, 0);
        }
    }

    // ---- stats finalize: reduce over k-groups (lane bits 4,5), broadcast
    float inv = 1.f / (float)(4 * bw);
    float mrow[4][4], rrow[4][4];
    #pragma unroll
    for (int mi = 0; mi < 4; ++mi) {
        float s = sA[mi], q = qA[mi];
        s += __shfl_xor(s, 16); s += __shfl_xor(s, 32);
        q += __shfl_xor(q, 16); q += __shfl_xor(q, 32);
        float mean = s * inv;
        float var  = fmaf(q, inv, -mean * mean);
        float rs   = rsqrtf(var + EPSF);
        #pragma unroll
        for (int j = 0; j < 4; ++j) {
            int src = (ksub << 2) + j;
            mrow[mi][j] = __shfl(mean, src);
            rrow[mi][j] = __shfl(rs, src);
        }
    }

    // ---- epilogue: z = rs*(acc - mean*s1) + s2
    float s1r[4], s2r[4];
    #pragma unroll
    for (int ni = 0; ni < 4; ++ni) {
        int e = ewave + ni * 16 + l15;
        s1r[ni] = s1a[n * EE + e];
        s2r[ni] = s2a[n * EE + e];
    }
    size_t outRow = ((size_t)(b * NB + n)) * TT;
    #pragma unroll
    for (int mi = 0; mi < 4; ++mi) {
        #pragma unroll
        for (int j = 0; j < 4; ++j) {
            int t = t0 + tband + mi * 16 + (ksub << 2) + j;
            float m = mrow[mi][j], r = rrow[mi][j];
            float* op = out + (outRow + t) * EE + ewave + l15;
            #pragma unroll
            for (int ni = 0; ni < 4; ++ni)
                op[ni * 16] = fmaf(r, acc[mi][ni][j] - m * s1r[ni], s2r[ni]);
        }
    }
}

// ---------------------------------------------------------------------------
extern "C" void kernel_launch(void* const* d_in, const int* in_sizes, int n_in,
                              void* d_out, int out_size, void* d_ws, size_t ws_size,
                              hipStream_t stream)
{
    const float* x      = (const float*)d_in[0];
    const float* gamma  = (const float*)d_in[1];
    const float* beta   = (const float*)d_in[2];
    const float* v      = (const float*)d_in[3];
    const float* g      = (const float*)d_in[4];
    const float* bias   = (const float*)d_in[5];
    const int*   bstart = (const int*)d_in[6];
    const int*   bwidth = (const int*)d_in[7];
    float* out = (float*)d_out;

    unsigned short* ATg = (unsigned short*)d_ws;                 // 37*9*128*32 bf16
    float* s1  = (float*)(ATg + (size_t)NB * CHS * EE * 32);     // 37*128 f32
    float* s2p = s1 + NB * EE;                                   // 37*128 f32

    prep_kernel<<<NB * 16, 256, 0, stream>>>(gamma, beta, v, g, bias, bwidth, ATg, s1, s2p);
    fused_kernel<<<BB * NB * 16, 256, 0, stream>>>(x, bstart, bwidth, ATg, s1, s2p, out);
}